// Round 7
// baseline (254.343 us; speedup 1.0000x reference)
//
#include <hip/hip_runtime.h>
#include <cmath>

// LocalHolder2D: out = w3*log10(maxpool3(x)) + w5*log10(maxpool5(x)) + w7*log10(maxpool7(x))
// x: (8,64,256,256) fp32, strictly positive => -inf padding == 0 padding.
// Separable maxpool: vertical (register rolling window) then horizontal
// (per-lane prefix/suffix maxes + lane+-1 DPP exchange). One wave = one full
// 256-wide row (64 lanes x float4). No LDS, no __syncthreads.
//
// R1: grid 512 -> 2048 blocks (4 bands/image), occupancy 20% -> 68%.
// R2/R3: DPP lane+-1 exchange. NEUTRAL -> LDS pipe not critical path.
// R4/R6 evidence: L3-warm dispatches run at same dur -> latency-bound.
//     R6's PF=4 register window produced VGPR=36 (< 44 needed) -> the
//     compiler SANK the prefetch loads to their uses, erasing the MLP.
// R7: pin each prefetch load with an empty `asm volatile` consuming its
//     components -> LLVM cannot sink a load past a volatile asm. PF=6.
//     Expect VGPR ~70-85 and fine-grained vmcnt(N) at the use point.

#define IMG_H 256
#define IMG_W 256
#define RPW   16   // rows per wave; 4 waves/block -> 64-row band per block
#define PF    6    // prefetch distance (loads in flight per wave)

typedef float vfloat4 __attribute__((ext_vector_type(4)));

// lane i <- lane i-1, zero at lane 0  (DPP wf_shr1; invalid lane -> old=0)
__device__ __forceinline__ float dpp_left(float v) {
  return __int_as_float(
      __builtin_amdgcn_update_dpp(0, __float_as_int(v), 0x138, 0xF, 0xF, true));
}
// lane i <- lane i+1, zero at lane 63 (DPP wf_shl1)
__device__ __forceinline__ float dpp_right(float v) {
  return __int_as_float(
      __builtin_amdgcn_update_dpp(0, __float_as_int(v), 0x130, 0xF, 0xF, true));
}

__device__ __forceinline__ float4 f4max(float4 a, float4 b) {
  return make_float4(fmaxf(a.x, b.x), fmaxf(a.y, b.y),
                     fmaxf(a.z, b.z), fmaxf(a.w, b.w));
}

// zero-instruction scheduling pin: the load producing v must issue before
// this point and cannot be sunk below it
__device__ __forceinline__ void pin(float4& v) {
  asm volatile("" : "+v"(v.x), "+v"(v.y), "+v"(v.z), "+v"(v.w));
}

struct PS { float p1, p2, p3, s1, s2, s3, f; };

__device__ __forceinline__ PS make_ps(float4 a) {
  PS r;
  r.p1 = a.x;
  r.p2 = fmaxf(a.x, a.y);
  r.p3 = fmaxf(r.p2, a.z);
  r.s1 = a.w;
  r.s2 = fmaxf(a.z, a.w);
  r.s3 = fmaxf(a.y, r.s2);
  r.f  = fmaxf(r.p2, r.s2);
  return r;
}

__global__ __launch_bounds__(256, 4) void holder_kernel(
    const float* __restrict__ x, float* __restrict__ out,
    float w3, float w5, float w7)
{
  const int lane = threadIdx.x & 63;
  const int wave = threadIdx.x >> 6;
  const int img  = blockIdx.x;
  const int band = blockIdx.y;
  const int r0   = band * (4 * RPW) + wave * RPW;

  const float* px = x   + (size_t)img * (IMG_H * IMG_W) + lane * 4;
  float*       po = out + (size_t)img * (IMG_H * IMG_W) + lane * 4;

  const float4 zero = make_float4(0.f, 0.f, 0.f, 0.f);

  // rolling window: win[i] = row (r-3+i), i = 0..6+PF  (rows r-3 .. r+3+PF)
  float4 win[7 + PF];
#pragma unroll
  for (int i = 0; i < 7 + PF; ++i) {
    int rr = r0 - 3 + i;
    win[i] = (rr >= 0 && rr < IMG_H) ? *(const float4*)(px + rr * IMG_W) : zero;
    pin(win[i]);
  }

#pragma unroll 4
  for (int r = r0; r < r0 + RPW; ++r) {
    // prefetch row r+4+PF, consumed PF iterations from now; mask rows the
    // band never consumes (> r0+RPW+2) -- wave-uniform predicate
    int rn = r + 4 + PF;
    float4 nxt = (rn < IMG_H && (rn - r0) < RPW + 3)
                     ? *(const float4*)(px + rn * IMG_W) : zero;
    pin(nxt);  // forbid sinking this load to its use PF iterations later

    // vertical maxes, radius 1/2/3 (rows r-3..r+3 = win[0..6])
    float4 v1 = f4max(f4max(win[2], win[3]), win[4]);
    float4 v2 = f4max(v1, f4max(win[1], win[5]));
    float4 v3 = f4max(v2, f4max(win[0], win[6]));

    PS a1 = make_ps(v1), a2 = make_ps(v2), a3 = make_ps(v3);

    // left-neighbor suffix maxes (lane-1); DPP zero-fills lane 0
    float L1s1 = dpp_left(a1.s1);
    float L2s1 = dpp_left(a2.s1);
    float L2s2 = dpp_left(a2.s2);
    float L3s1 = dpp_left(a3.s1);
    float L3s2 = dpp_left(a3.s2);
    float L3s3 = dpp_left(a3.s3);

    // right-neighbor prefix maxes (lane+1); DPP zero-fills lane 63
    float R1p1 = dpp_right(a1.p1);
    float R2p1 = dpp_right(a2.p1);
    float R2p2 = dpp_right(a2.p2);
    float R3p1 = dpp_right(a3.p1);
    float R3p2 = dpp_right(a3.p2);
    float R3p3 = dpp_right(a3.p3);

    // horizontal maxes per column j=0..3 (thread columns 4*lane + j)
    float m3_0 = fmaxf(L1s1, a1.p2);
    float m3_1 = a1.p3;
    float m3_2 = a1.s3;
    float m3_3 = fmaxf(a1.s2, R1p1);

    float m5_0 = fmaxf(L2s2, a2.p3);
    float m5_1 = fmaxf(L2s1, a2.f);
    float m5_2 = fmaxf(a2.f, R2p1);
    float m5_3 = fmaxf(a2.s3, R2p2);

    float m7_0 = fmaxf(L3s3, a3.f);
    float m7_1 = fmaxf(fmaxf(L3s2, a3.f), R3p1);
    float m7_2 = fmaxf(fmaxf(L3s1, a3.f), R3p2);
    float m7_3 = fmaxf(a3.f, R3p3);

    // weights already include log10(2): out = sum w_i * log2(m_i)
    vfloat4 o;
    o.x = fmaf(w7, __log2f(m7_0), fmaf(w5, __log2f(m5_0), w3 * __log2f(m3_0)));
    o.y = fmaf(w7, __log2f(m7_1), fmaf(w5, __log2f(m5_1), w3 * __log2f(m3_1)));
    o.z = fmaf(w7, __log2f(m7_2), fmaf(w5, __log2f(m5_2), w3 * __log2f(m3_2)));
    o.w = fmaf(w7, __log2f(m7_3), fmaf(w5, __log2f(m5_3), w3 * __log2f(m3_3)));
    __builtin_nontemporal_store(o, (vfloat4*)(po + r * IMG_W));

    // slide window down one row
#pragma unroll
    for (int i = 0; i < 6 + PF; ++i) win[i] = win[i + 1];
    win[6 + PF] = nxt;
  }
}

extern "C" void kernel_launch(void* const* d_in, const int* in_sizes, int n_in,
                              void* d_out, int out_size, void* d_ws, size_t ws_size,
                              hipStream_t stream) {
  const float* x = (const float*)d_in[0];
  float* out = (float*)d_out;

  const int n_img = in_sizes[0] / (IMG_H * IMG_W);  // B*C = 512

  // closed-form OLS slope weights (H*W cancels in centering), log10(2) folded in
  const double l0 = log10(3.0), l1 = log10(5.0), l2 = log10(7.0);
  const double m  = (l0 + l1 + l2) / 3.0;
  const double c0 = l0 - m, c1 = l1 - m, c2 = l2 - m;
  const double s  = c0 * c0 + c1 * c1 + c2 * c2;
  const double LG2 = 0.30102999566398119521;  // log10(2)
  const float w3 = (float)(c0 / s * LG2);
  const float w5 = (float)(c1 / s * LG2);
  const float w7 = (float)(c2 / s * LG2);

  hipLaunchKernelGGL(holder_kernel, dim3(n_img, 4), dim3(256), 0, stream,
                     x, out, w3, w5, w7);
}

// Round 8
// 234.126 us; speedup vs baseline: 1.0863x; 1.0863x over previous
//
#include <hip/hip_runtime.h>
#include <cmath>

// LocalHolder2D: out = w3*log10(maxpool3(x)) + w5*log10(maxpool5(x)) + w7*log10(maxpool7(x))
// x: (8,64,256,256) fp32, strictly positive => -inf padding == 0 padding.
// Separable maxpool; one wave = one 256-wide row (64 lanes x float4).
//
// R1: 2048 blocks (4 bands/image), occupancy 20%->68%.
// R2-R4: DPP lane+-1 exchange (neutral). L3-warm dispatches run at same
//     dur -> latency/MLP-bound, not BW-bound. VALU time invariant ~22us.
// R6/R7: C-level prefetch windows defeated by compiler (VGPR stuck at 36,
//     loads sunk to uses; pins only added overhead).
// R8: inline-asm software pipeline, 4-row chunks, 10-row register window.
//     Volatile global_load_dwordx4 for chunk k+1 issued BEFORE chunk k's
//     compute; s_waitcnt vmcnt(4) asm with "+v" ties on the landing regs
//     (vmcnt FIFO: 4 prev stores + 4 loads + 4 cur stores = 12 -> wait(4)
//     drains the loads, leaves cur stores pending). Addresses clamped to
//     [0,255]; out-of-range rows zeroed post-wait (wave-uniform).

#define IMG_H 256
#define IMG_W 256
#define RPW   16   // rows per wave; 4 waves/block -> 64-row band per block
#define CH    4    // rows per chunk (loads in flight per wave)

typedef float vf4 __attribute__((ext_vector_type(4)));

// volatile asm load: compiler cannot sink/reorder it (memory clobber +
// volatile); issues exactly where placed. saddr form: mem[s[base] + voff].
__device__ __forceinline__ vf4 aload(const float* base, uint32_t voff) {
  vf4 r;
  asm volatile("global_load_dwordx4 %0, %1, %2"
               : "=v"(r) : "v"(voff), "s"(base) : "memory");
  return r;
}

// wait until <=4 vmem ops outstanding; "+v" ties force all consumers of
// a..d to be scheduled after the wait.
__device__ __forceinline__ void wait4(vf4& a, vf4& b, vf4& c, vf4& d) {
  asm volatile("s_waitcnt vmcnt(4)"
               : "+v"(a), "+v"(b), "+v"(c), "+v"(d) :: "memory");
}

__device__ __forceinline__ void wait0_10(vf4& a, vf4& b, vf4& c, vf4& d,
                                         vf4& e, vf4& f, vf4& g, vf4& h,
                                         vf4& i, vf4& j) {
  asm volatile("s_waitcnt vmcnt(0)"
               : "+v"(a), "+v"(b), "+v"(c), "+v"(d), "+v"(e),
                 "+v"(f), "+v"(g), "+v"(h), "+v"(i), "+v"(j) :: "memory");
}

// lane i <- lane i-1, zero at lane 0  (DPP wf_shr1; invalid lane -> old=0)
__device__ __forceinline__ float dpp_left(float v) {
  return __int_as_float(
      __builtin_amdgcn_update_dpp(0, __float_as_int(v), 0x138, 0xF, 0xF, true));
}
// lane i <- lane i+1, zero at lane 63 (DPP wf_shl1)
__device__ __forceinline__ float dpp_right(float v) {
  return __int_as_float(
      __builtin_amdgcn_update_dpp(0, __float_as_int(v), 0x130, 0xF, 0xF, true));
}

__device__ __forceinline__ vf4 vmax(vf4 a, vf4 b) {
  vf4 r;
  r.x = fmaxf(a.x, b.x); r.y = fmaxf(a.y, b.y);
  r.z = fmaxf(a.z, b.z); r.w = fmaxf(a.w, b.w);
  return r;
}

struct PS { float p1, p2, p3, s1, s2, s3, f; };

__device__ __forceinline__ PS make_ps(vf4 a) {
  PS r;
  r.p1 = a.x;
  r.p2 = fmaxf(a.x, a.y);
  r.p3 = fmaxf(r.p2, a.z);
  r.s1 = a.w;
  r.s2 = fmaxf(a.z, a.w);
  r.s3 = fmaxf(a.y, r.s2);
  r.f  = fmaxf(r.p2, r.s2);
  return r;
}

__global__ __launch_bounds__(256, 4) void holder_kernel(
    const float* __restrict__ x, float* __restrict__ out,
    float w3, float w5, float w7)
{
  const int lane = threadIdx.x & 63;
  const int wave = threadIdx.x >> 6;
  const int img  = blockIdx.x;
  const int band = blockIdx.y;
  const int r0   = band * (4 * RPW) + wave * RPW;

  const float* px = x + (size_t)img * (IMG_H * IMG_W);       // base (SGPR)
  float*       po = out + (size_t)img * (IMG_H * IMG_W) + lane * 4;
  const uint32_t lo = (uint32_t)lane * 16u;                  // byte offset in row

  const vf4 vzero = (vf4)0.0f;

  // window w[i] = input row (R-3+i), i=0..9, for current chunk at row R
  vf4 w[10];
#pragma unroll
  for (int i = 0; i < 10; ++i) {
    int rr = r0 - 3 + i;
    int rc = rr < 0 ? 0 : (rr > IMG_H - 1 ? IMG_H - 1 : rr);
    w[i] = aload(px, (uint32_t)(rc * IMG_W * 4) + lo);
  }
  wait0_10(w[0], w[1], w[2], w[3], w[4], w[5], w[6], w[7], w[8], w[9]);
#pragma unroll
  for (int i = 0; i < 10; ++i) {
    int rr = r0 - 3 + i;
    if (rr < 0 || rr >= IMG_H) w[i] = vzero;
  }

#pragma unroll
  for (int c = 0; c < RPW / CH; ++c) {
    const int R = r0 + c * CH;

    // ---- issue next chunk's 4 row loads (rows R+7..R+10, clamped) ----
    vf4 nw[CH];
#pragma unroll
    for (int j = 0; j < CH; ++j) {
      int rr = R + 7 + j;
      int rc = rr > IMG_H - 1 ? IMG_H - 1 : rr;
      nw[j] = aload(px, (uint32_t)(rc * IMG_W * 4) + lo);
    }

    // ---- compute + store output rows R..R+3 from w[0..9] ----
#pragma unroll
    for (int j = 0; j < CH; ++j) {
      vf4 v1 = vmax(vmax(w[j + 2], w[j + 3]), w[j + 4]);
      vf4 v2 = vmax(v1, vmax(w[j + 1], w[j + 5]));
      vf4 v3 = vmax(v2, vmax(w[j + 0], w[j + 6]));

      PS a1 = make_ps(v1), a2 = make_ps(v2), a3 = make_ps(v3);

      float L1s1 = dpp_left(a1.s1);
      float L2s1 = dpp_left(a2.s1);
      float L2s2 = dpp_left(a2.s2);
      float L3s1 = dpp_left(a3.s1);
      float L3s2 = dpp_left(a3.s2);
      float L3s3 = dpp_left(a3.s3);

      float R1p1 = dpp_right(a1.p1);
      float R2p1 = dpp_right(a2.p1);
      float R2p2 = dpp_right(a2.p2);
      float R3p1 = dpp_right(a3.p1);
      float R3p2 = dpp_right(a3.p2);
      float R3p3 = dpp_right(a3.p3);

      float m3_0 = fmaxf(L1s1, a1.p2);
      float m3_1 = a1.p3;
      float m3_2 = a1.s3;
      float m3_3 = fmaxf(a1.s2, R1p1);

      float m5_0 = fmaxf(L2s2, a2.p3);
      float m5_1 = fmaxf(L2s1, a2.f);
      float m5_2 = fmaxf(a2.f, R2p1);
      float m5_3 = fmaxf(a2.s3, R2p2);

      float m7_0 = fmaxf(L3s3, a3.f);
      float m7_1 = fmaxf(fmaxf(L3s2, a3.f), R3p1);
      float m7_2 = fmaxf(fmaxf(L3s1, a3.f), R3p2);
      float m7_3 = fmaxf(a3.f, R3p3);

      vf4 o;
      o.x = fmaf(w7, __log2f(m7_0), fmaf(w5, __log2f(m5_0), w3 * __log2f(m3_0)));
      o.y = fmaf(w7, __log2f(m7_1), fmaf(w5, __log2f(m5_1), w3 * __log2f(m3_1)));
      o.z = fmaf(w7, __log2f(m7_2), fmaf(w5, __log2f(m5_2), w3 * __log2f(m3_2)));
      o.w = fmaf(w7, __log2f(m7_3), fmaf(w5, __log2f(m5_3), w3 * __log2f(m3_3)));
      __builtin_nontemporal_store(o, (vf4*)(po + (R + j) * IMG_W));
    }

    // ---- drain the 4 loads (leaves this chunk's stores in flight) ----
    wait4(nw[0], nw[1], nw[2], nw[3]);

    // zero-fix rows past the image bottom, then shift window by CH
#pragma unroll
    for (int j = 0; j < CH; ++j) {
      int rr = R + 7 + j;
      if (rr >= IMG_H) nw[j] = vzero;
    }
#pragma unroll
    for (int i = 0; i < 10 - CH; ++i) w[i] = w[i + CH];
#pragma unroll
    for (int j = 0; j < CH; ++j) w[10 - CH + j] = nw[j];
  }
}

extern "C" void kernel_launch(void* const* d_in, const int* in_sizes, int n_in,
                              void* d_out, int out_size, void* d_ws, size_t ws_size,
                              hipStream_t stream) {
  const float* x = (const float*)d_in[0];
  float* out = (float*)d_out;

  const int n_img = in_sizes[0] / (IMG_H * IMG_W);  // B*C = 512

  // closed-form OLS slope weights (H*W cancels in centering), log10(2) folded in
  const double l0 = log10(3.0), l1 = log10(5.0), l2 = log10(7.0);
  const double m  = (l0 + l1 + l2) / 3.0;
  const double c0 = l0 - m, c1 = l1 - m, c2 = l2 - m;
  const double s  = c0 * c0 + c1 * c1 + c2 * c2;
  const double LG2 = 0.30102999566398119521;  // log10(2)
  const float w3 = (float)(c0 / s * LG2);
  const float w5 = (float)(c1 / s * LG2);
  const float w7 = (float)(c2 / s * LG2);

  hipLaunchKernelGGL(holder_kernel, dim3(n_img, 4), dim3(256), 0, stream,
                     x, out, w3, w5, w7);
}